// Round 8
// baseline (6090.218 us; speedup 1.0000x reference)
//
#include <hip/hip_runtime.h>
#include <hip/hip_bf16.h>

#define BATCH 64
#define SEQ   512
#define ISZ   1024
#define HID   1024
#define OUTSEQ_ELEMS (BATCH * SEQ * HID)   // 33554432
#define NGRP  2              // independent batch groups (32 batches each)
#define NCB   16             // col-blocks per group
#define GB    32             // batches per group
#define BCOLS 64             // hidden cols per block
#define NBLK  (NGRP * NCB)   // 32 blocks
#define FSTR  16             // flag stride in u32 (64 B)

typedef float f32x4 __attribute__((ext_vector_type(4)));
typedef short bf16x8 __attribute__((ext_vector_type(8)));

__device__ __forceinline__ unsigned short f2bf(float f) {
    union { float f; unsigned u; } v; v.f = f;
    unsigned r = v.u + 0x7fffu + ((v.u >> 16) & 1u);   // RNE
    return (unsigned short)(r >> 16);
}

// Coherence-point (IC) read, bypassing L1+L2.
__device__ __forceinline__ unsigned ld_ic(const unsigned int* p) {
    unsigned v;
    asm volatile("global_load_dword %0, %1, off sc0 sc1\n\ts_waitcnt vmcnt(0)"
                 : "=v"(v) : "v"(p) : "memory");
    return v;
}

// ---------------------------------------------------------------------------
// Kernel A: xp[m][n] = input[m][:] . Wx[:][n] + b[n]  -> written into d_out.
// (unchanged since R1 — proven, ~180 us)
// ---------------------------------------------------------------------------
__global__ __launch_bounds__(256)
void xproj_gemm(const float* __restrict__ A, const float* __restrict__ W,
                const float* __restrict__ bias, float* __restrict__ C)
{
    __shared__ __align__(16) unsigned short As[128][72];
    __shared__ __align__(16) unsigned short Bs[128][72];
    const int tid  = threadIdx.x;
    const int lane = tid & 63;
    const int wave = tid >> 6;
    const int m0 = blockIdx.y * 128;
    const int n0 = blockIdx.x * 128;
    const int wm = (wave >> 1) * 64;
    const int wn = (wave & 1) * 64;
    const int l15 = lane & 15;
    const int kq8 = (lane >> 4) * 8;

    f32x4 acc[4][4] = {};

    for (int k0 = 0; k0 < ISZ; k0 += 64) {
        #pragma unroll
        for (int i = 0; i < 8; ++i) {
            int idx = tid + i * 256;
            int row = idx >> 4;
            int kq  = idx & 15;
            float4 v = *reinterpret_cast<const float4*>(
                A + (size_t)(m0 + row) * ISZ + k0 + kq * 4);
            unsigned short* dst = &As[row][kq * 4];
            dst[0] = f2bf(v.x); dst[1] = f2bf(v.y);
            dst[2] = f2bf(v.z); dst[3] = f2bf(v.w);
        }
        #pragma unroll
        for (int i = 0; i < 8; ++i) {
            int idx = tid + i * 256;
            int kk = idx >> 5;
            int nq = idx & 31;
            float4 v = *reinterpret_cast<const float4*>(
                W + (size_t)(k0 + kk) * HID + n0 + nq * 4);
            Bs[nq * 4 + 0][kk] = f2bf(v.x);
            Bs[nq * 4 + 1][kk] = f2bf(v.y);
            Bs[nq * 4 + 2][kk] = f2bf(v.z);
            Bs[nq * 4 + 3][kk] = f2bf(v.w);
        }
        __syncthreads();
        #pragma unroll
        for (int kk = 0; kk < 64; kk += 32) {
            const int krd = kk + kq8;
            bf16x8 a[4], b[4];
            #pragma unroll
            for (int mf = 0; mf < 4; ++mf)
                a[mf] = *reinterpret_cast<const bf16x8*>(&As[wm + mf * 16 + l15][krd]);
            #pragma unroll
            for (int nf = 0; nf < 4; ++nf)
                b[nf] = *reinterpret_cast<const bf16x8*>(&Bs[wn + nf * 16 + l15][krd]);
            #pragma unroll
            for (int mf = 0; mf < 4; ++mf)
                #pragma unroll
                for (int nf = 0; nf < 4; ++nf)
                    acc[mf][nf] = __builtin_amdgcn_mfma_f32_16x16x32_bf16(
                        a[mf], b[nf], acc[mf][nf], 0, 0, 0);
        }
        __syncthreads();
    }

    const int r4 = (lane >> 4) * 4;
    #pragma unroll
    for (int nf = 0; nf < 4; ++nf) {
        int col = n0 + wn + nf * 16 + l15;
        float bv = bias[col];
        #pragma unroll
        for (int mf = 0; mf < 4; ++mf) {
            int row = m0 + wm + mf * 16 + r4;
            #pragma unroll
            for (int r = 0; r < 4; ++r)
                C[(size_t)(row + r) * HID + col] = acc[mf][nf][r] + bv;
        }
    }
}

// ---------------------------------------------------------------------------
// Kernel B: R6 geometry (2 groups x 16 col-blocks; block = 32 batches x 64
// cols, Wh slice in LDS). NEW publish protocol, no fences:
//   write h via RETURNING b64 atomic exchanges (ack = executed at coherence
//   point) -> vmcnt(0) -> syncthreads -> flag via returning exchange.
//   readers: poll flags with sc0 sc1 loads; read h with sc0 sc1 loads.
// ---------------------------------------------------------------------------
__global__ __launch_bounds__(512, 1)
void rnn_steps(const float* __restrict__ W, const float* __restrict__ h0,
               float* __restrict__ out,
               unsigned short* __restrict__ hA, unsigned short* __restrict__ hB,
               unsigned int* __restrict__ flags)
{
    __shared__ __align__(16) unsigned short Bsh[BCOLS][1032];   // 132 KB
    const int tid  = threadIdx.x;
    const int lane = tid & 63;
    const int wave = tid >> 6;
    const int g  = blockIdx.x >> 4;        // batch group 0..1
    const int cb = blockIdx.x & 15;        // col-block 0..15
    const int c0 = cb * BCOLS;
    const int mt = wave >> 2;              // M-tile (batches 16*mt..+16)
    const int nt = wave & 3;               // N-tile (cols 16*nt..+16)
    const int l15 = lane & 15;
    const int kq8 = (lane >> 4) * 8;

    // ---- stage Wh cols [c0, c0+64) -> Bsh[col][k] bf16 (once) ----
    for (int idx = tid; idx < 16 * 1024; idx += 512) {
        int k  = idx >> 4;
        int c4 = (idx & 15) * 4;
        float4 v = *reinterpret_cast<const float4*>(
            W + (size_t)(ISZ + k) * HID + c0 + c4);
        Bsh[c4 + 0][k] = f2bf(v.x);
        Bsh[c4 + 1][k] = f2bf(v.y);
        Bsh[c4 + 2][k] = f2bf(v.z);
        Bsh[c4 + 3][k] = f2bf(v.w);
    }
    // ---- init h_0 rows [32g,+32) x cols [c0,+64) via returning exchanges ----
    {
        int b  = tid >> 4;                 // 0..31
        int c4 = (tid & 15) * 4;
        float4 v = *reinterpret_cast<const float4*>(
            h0 + (size_t)(g * GB + b) * HID + c0 + c4);
        unsigned long long d =  (unsigned long long)f2bf(v.x)
                             | ((unsigned long long)f2bf(v.y) << 16)
                             | ((unsigned long long)f2bf(v.z) << 32)
                             | ((unsigned long long)f2bf(v.w) << 48);
        unsigned long long old = __hip_atomic_exchange(
            (unsigned long long*)(hA + (size_t)(g * GB + b) * HID + c0 + c4),
            d, __ATOMIC_RELAXED, __HIP_MEMORY_SCOPE_AGENT);
        asm volatile("" :: "v"(old));      // force returning form
    }
    asm volatile("s_waitcnt vmcnt(0)" ::: "memory");
    __syncthreads();
    if (tid == 0) {
        unsigned o = __hip_atomic_exchange(flags + (g * NCB + cb) * FSTR, 1u,
                                           __ATOMIC_RELAXED,
                                           __HIP_MEMORY_SCOPE_AGENT);
        asm volatile("" :: "v"(o));
    }

    unsigned int* gfl = flags + g * NCB * FSTR;
    const int arowg = g * GB + mt * 16 + l15;            // A-operand global row
    const unsigned short* ab0 = hA + (size_t)arowg * HID + kq8;
    const unsigned short* ab1 = hB + (size_t)arowg * HID + kq8;
    const int orow = g * GB + mt * 16 + (lane >> 4) * 4; // output batch base
    const int gcol = c0 + nt * 16 + l15;                 // output column
    const unsigned short* bbase = &Bsh[nt * 16 + l15][kq8];

    float xpv[4];
    #pragma unroll
    for (int j = 0; j < 4; ++j)
        xpv[j] = out[(size_t)(orow + j) * (SEQ * HID) + gcol];

    for (int t = 0; t < SEQ; ++t) {
        // ---- wait: all 16 group flags >= t+1 (IC reads, no fence) ----
        if (wave == 0) {
            int guard = 0;
            for (;;) {
                unsigned v = (lane < NCB) ? ld_ic(gfl + lane * FSTR) : 0xFFFFFFFFu;
                if (__all(v >= (unsigned)(t + 1))) break;
                if (++guard > (1 << 20)) break;   // degrade, never hang
                __builtin_amdgcn_s_sleep(1);
            }
        }
        __syncthreads();

        const unsigned short* ap = (t & 1) ? ab1 : ab0;
        unsigned short*       nx = (t & 1) ? hA : hB;

        // ---- A fragments: coherence-point loads (data committed via RMW) ----
        bf16x8 Af[32];
        #pragma unroll
        for (int ks = 0; ks < 32; ++ks)
            asm volatile("global_load_dwordx4 %0, %1, off offset:%2 sc0 sc1"
                         : "=v"(Af[ks]) : "v"(ap), "i"(ks * 64) : "memory");
        asm volatile("s_waitcnt vmcnt(0)" ::: "memory");
        __builtin_amdgcn_sched_barrier(0);

        f32x4 ac0 = {}, ac1 = {}, ac2 = {}, ac3 = {};
        #pragma unroll
        for (int ks = 0; ks < 32; ks += 4) {
            bf16x8 b0 = *reinterpret_cast<const bf16x8*>(bbase + (ks + 0) * 32);
            bf16x8 b1 = *reinterpret_cast<const bf16x8*>(bbase + (ks + 1) * 32);
            bf16x8 b2 = *reinterpret_cast<const bf16x8*>(bbase + (ks + 2) * 32);
            bf16x8 b3 = *reinterpret_cast<const bf16x8*>(bbase + (ks + 3) * 32);
            ac0 = __builtin_amdgcn_mfma_f32_16x16x32_bf16(Af[ks + 0], b0, ac0, 0, 0, 0);
            ac1 = __builtin_amdgcn_mfma_f32_16x16x32_bf16(Af[ks + 1], b1, ac1, 0, 0, 0);
            ac2 = __builtin_amdgcn_mfma_f32_16x16x32_bf16(Af[ks + 2], b2, ac2, 0, 0, 0);
            ac3 = __builtin_amdgcn_mfma_f32_16x16x32_bf16(Af[ks + 3], b3, ac3, 0, 0, 0);
        }
        f32x4 acc = (ac0 + ac1) + (ac2 + ac3);

        float hv[4];
        #pragma unroll
        for (int j = 0; j < 4; ++j)
            hv[j] = tanhf(acc[j] + xpv[j]);

        // ---- publish h: pack 4 neighbor cols -> b64 returning exchange ----
        // lanes 4k..4k+3 hold cols gcol..gcol+3 of the same rows
        #pragma unroll
        for (int j = 0; j < 4; ++j) {
            unsigned u  = (unsigned)f2bf(hv[j]);
            int base = lane & ~3;
            unsigned u0 = __shfl(u, base + 0);
            unsigned u1 = __shfl(u, base + 1);
            unsigned u2 = __shfl(u, base + 2);
            unsigned u3 = __shfl(u, base + 3);
            if ((lane & 3) == 0) {
                unsigned long long d =  (unsigned long long)u0
                                     | ((unsigned long long)u1 << 16)
                                     | ((unsigned long long)u2 << 32)
                                     | ((unsigned long long)u3 << 48);
                unsigned long long old = __hip_atomic_exchange(
                    (unsigned long long*)(nx + (size_t)(orow + j) * HID + gcol),
                    d, __ATOMIC_RELAXED, __HIP_MEMORY_SCOPE_AGENT);
                asm volatile("" :: "v"(old));
            }
        }
        asm volatile("s_waitcnt vmcnt(0)" ::: "memory");   // exchanges executed
        __syncthreads();                                    // all waves done
        if (t < SEQ - 1 && tid == 0) {
            unsigned o = __hip_atomic_exchange(gfl + cb * FSTR, (unsigned)(t + 2),
                                               __ATOMIC_RELAXED,
                                               __HIP_MEMORY_SCOPE_AGENT);
            asm volatile("" :: "v"(o));
        }

        // ---- self-owned fp32 outputs (plain) + next xp prefetch ----
        #pragma unroll
        for (int j = 0; j < 4; ++j)
            out[(size_t)(orow + j) * (SEQ * HID) + (size_t)t * HID + gcol] = hv[j];
        if (t == SEQ - 1) {
            #pragma unroll
            for (int j = 0; j < 4; ++j)
                out[(size_t)OUTSEQ_ELEMS + (size_t)(orow + j) * HID + gcol] = hv[j];
        } else {
            #pragma unroll
            for (int j = 0; j < 4; ++j)
                xpv[j] = out[(size_t)(orow + j) * (SEQ * HID)
                             + (size_t)(t + 1) * HID + gcol];
        }
    }
}

extern "C" void kernel_launch(void* const* d_in, const int* in_sizes, int n_in,
                              void* d_out, int out_size, void* d_ws, size_t ws_size,
                              hipStream_t stream)
{
    const float* input = (const float*)d_in[0];
    const float* h0    = (const float*)d_in[1];
    const float* W     = (const float*)d_in[2];
    const float* bias  = (const float*)d_in[3];
    float* out = (float*)d_out;

    unsigned short* hA = (unsigned short*)d_ws;
    unsigned short* hB = hA + (size_t)BATCH * HID;
    unsigned int* flags =
        (unsigned int*)((char*)d_ws + (size_t)2 * BATCH * HID * sizeof(unsigned short));

    dim3 gA(HID / 128, (BATCH * SEQ) / 128);   // (8, 256)
    xproj_gemm<<<gA, dim3(256), 0, stream>>>(input, W, bias, out);

    hipMemsetAsync(flags, 0, NBLK * FSTR * sizeof(unsigned int), stream);

    rnn_steps<<<dim3(NBLK), dim3(512), 0, stream>>>(W, h0, out, hA, hB, flags);
}

// Round 9
// 2770.166 us; speedup vs baseline: 2.1985x; 2.1985x over previous
//
#include <hip/hip_runtime.h>
#include <hip/hip_bf16.h>

#define BATCH 64
#define SEQ   512
#define ISZ   1024
#define HID   1024
#define OUTSEQ_ELEMS (BATCH * SEQ * HID)   // 33554432
#define NBG   4              // batch groups (16 batches each)
#define NCG   16             // col groups (64 cols each)
#define NBLK  (NBG * NCG)    // 64 blocks
#define FSTR  16             // flag stride in u32 (64 B)

typedef float f32x4 __attribute__((ext_vector_type(4)));
typedef short bf16x8 __attribute__((ext_vector_type(8)));

__device__ __forceinline__ unsigned short f2bf(float f) {
    union { float f; unsigned u; } v; v.f = f;
    unsigned r = v.u + 0x7fffu + ((v.u >> 16) & 1u);   // RNE
    return (unsigned short)(r >> 16);
}

// IC-direct flag read (proven R8)
__device__ __forceinline__ unsigned ld_ic(const unsigned int* p) {
    unsigned v;
    asm volatile("global_load_dword %0, %1, off sc0 sc1\n\ts_waitcnt vmcnt(0)"
                 : "=v"(v) : "v"(p) : "memory");
    return v;
}
// returning exchange: vmcnt-ack == executed at coherence point (proven R8)
__device__ __forceinline__ void exch64(unsigned long long* p, unsigned long long d) {
    unsigned long long old = __hip_atomic_exchange(p, d, __ATOMIC_RELAXED,
                                                   __HIP_MEMORY_SCOPE_AGENT);
    asm volatile("" :: "v"(old));
}
__device__ __forceinline__ void exch32(unsigned int* p, unsigned d) {
    unsigned old = __hip_atomic_exchange(p, d, __ATOMIC_RELAXED,
                                         __HIP_MEMORY_SCOPE_AGENT);
    asm volatile("" :: "v"(old));
}

// ---------------------------------------------------------------------------
// Kernel A: xp[m][n] = input[m][:] . Wx[:][n] + b[n]  -> written into d_out.
// (unchanged since R1 — proven, ~180 us)
// ---------------------------------------------------------------------------
__global__ __launch_bounds__(256)
void xproj_gemm(const float* __restrict__ A, const float* __restrict__ W,
                const float* __restrict__ bias, float* __restrict__ C)
{
    __shared__ __align__(16) unsigned short As[128][72];
    __shared__ __align__(16) unsigned short Bs[128][72];
    const int tid  = threadIdx.x;
    const int lane = tid & 63;
    const int wave = tid >> 6;
    const int m0 = blockIdx.y * 128;
    const int n0 = blockIdx.x * 128;
    const int wm = (wave >> 1) * 64;
    const int wn = (wave & 1) * 64;
    const int l15 = lane & 15;
    const int kq8 = (lane >> 4) * 8;

    f32x4 acc[4][4] = {};

    for (int k0 = 0; k0 < ISZ; k0 += 64) {
        #pragma unroll
        for (int i = 0; i < 8; ++i) {
            int idx = tid + i * 256;
            int row = idx >> 4;
            int kq  = idx & 15;
            float4 v = *reinterpret_cast<const float4*>(
                A + (size_t)(m0 + row) * ISZ + k0 + kq * 4);
            unsigned short* dst = &As[row][kq * 4];
            dst[0] = f2bf(v.x); dst[1] = f2bf(v.y);
            dst[2] = f2bf(v.z); dst[3] = f2bf(v.w);
        }
        #pragma unroll
        for (int i = 0; i < 8; ++i) {
            int idx = tid + i * 256;
            int kk = idx >> 5;
            int nq = idx & 31;
            float4 v = *reinterpret_cast<const float4*>(
                W + (size_t)(k0 + kk) * HID + n0 + nq * 4);
            Bs[nq * 4 + 0][kk] = f2bf(v.x);
            Bs[nq * 4 + 1][kk] = f2bf(v.y);
            Bs[nq * 4 + 2][kk] = f2bf(v.z);
            Bs[nq * 4 + 3][kk] = f2bf(v.w);
        }
        __syncthreads();
        #pragma unroll
        for (int kk = 0; kk < 64; kk += 32) {
            const int krd = kk + kq8;
            bf16x8 a[4], b[4];
            #pragma unroll
            for (int mf = 0; mf < 4; ++mf)
                a[mf] = *reinterpret_cast<const bf16x8*>(&As[wm + mf * 16 + l15][krd]);
            #pragma unroll
            for (int nf = 0; nf < 4; ++nf)
                b[nf] = *reinterpret_cast<const bf16x8*>(&Bs[wn + nf * 16 + l15][krd]);
            #pragma unroll
            for (int mf = 0; mf < 4; ++mf)
                #pragma unroll
                for (int nf = 0; nf < 4; ++nf)
                    acc[mf][nf] = __builtin_amdgcn_mfma_f32_16x16x32_bf16(
                        a[mf], b[nf], acc[mf][nf], 0, 0, 0);
        }
        __syncthreads();
    }

    const int r4 = (lane >> 4) * 4;
    #pragma unroll
    for (int nf = 0; nf < 4; ++nf) {
        int col = n0 + wn + nf * 16 + l15;
        float bv = bias[col];
        #pragma unroll
        for (int mf = 0; mf < 4; ++mf) {
            int row = m0 + wm + mf * 16 + r4;
            #pragma unroll
            for (int r = 0; r < 4; ++r)
                C[(size_t)(row + r) * HID + col] = acc[mf][nf][r] + bv;
        }
    }
}

// ---------------------------------------------------------------------------
// Kernel B: 2-D dataflow RNN. Block (i,j): i = batch-group (16 rows),
// j = col-group (64 cols). Per step: poll 16 flags (i,*) -> cooperative
// sc0sc1 stage of the 16x1024 A-stripe into LDS (dedup) -> 32 MFMA with
// Wh in 128 VGPRs/lane -> tanh -> publish 2KB via b64 returning exchanges
// -> flag exchange. No fences anywhere (R8-proven primitives only).
// ---------------------------------------------------------------------------
__global__ __launch_bounds__(256, 1)
void rnn_flow(const float* __restrict__ W, const float* __restrict__ h0,
              float* __restrict__ out,
              unsigned short* __restrict__ hA, unsigned short* __restrict__ hB,
              unsigned int* __restrict__ flags)
{
    __shared__ __align__(16) unsigned short lds[16 * 1032];   // 33 KB
    const int tid  = threadIdx.x;
    const int lane = tid & 63;
    const int wave = tid >> 6;              // = nt (col sub-tile)
    const int bg = blockIdx.x >> 4;         // batch-group 0..3
    const int cg = blockIdx.x & 15;         // col-group 0..15
    const int b0 = bg * 16;
    const int c0 = cg * 64;
    const int l15 = lane & 15;
    const int kq8 = (lane >> 4) * 8;
    const int q4  = (lane >> 4) * 4;

    // ---- publish own h_0 slice (16 rows x 64 cols) via exchanges ----
    {
        int row = tid >> 4;
        int c4  = (tid & 15) * 4;
        float4 v = *reinterpret_cast<const float4*>(
            h0 + (size_t)(b0 + row) * HID + c0 + c4);
        unsigned long long d =  (unsigned long long)f2bf(v.x)
                             | ((unsigned long long)f2bf(v.y) << 16)
                             | ((unsigned long long)f2bf(v.z) << 32)
                             | ((unsigned long long)f2bf(v.w) << 48);
        exch64((unsigned long long*)(hA + (size_t)(b0 + row) * HID + c0 + c4), d);
    }
    asm volatile("s_waitcnt vmcnt(0)" ::: "memory");
    __syncthreads();
    if (tid == 0) exch32(flags + (bg * NCG + cg) * FSTR, 1u);

    // ---- Wh cols [c0, c0+64) -> bfr (128 VGPR/lane), 4 LDS passes ----
    bf16x8 bfr[32];
    for (int w = 0; w < 4; ++w) {
        #pragma unroll 4
        for (int p = 0; p < 16; ++p) {
            int k  = p * 64 + (tid >> 2);
            int cc = (tid & 3) * 4;
            float4 v = *reinterpret_cast<const float4*>(
                W + (size_t)(ISZ + k) * HID + c0 + w * 16 + cc);
            lds[(cc + 0) * 1032 + k] = f2bf(v.x);
            lds[(cc + 1) * 1032 + k] = f2bf(v.y);
            lds[(cc + 2) * 1032 + k] = f2bf(v.z);
            lds[(cc + 3) * 1032 + k] = f2bf(v.w);
        }
        __syncthreads();
        if (wave == w) {
            #pragma unroll
            for (int ks = 0; ks < 32; ++ks)
                bfr[ks] = *reinterpret_cast<const bf16x8*>(
                    &lds[l15 * 1032 + ks * 32 + kq8]);
        }
        __syncthreads();
    }

    const int gcol = c0 + wave * 16 + l15;       // this lane's output column
    unsigned int* myfl = flags + bg * NCG * FSTR;

    float xpv[4];
    #pragma unroll
    for (int j = 0; j < 4; ++j)
        xpv[j] = out[(size_t)(b0 + q4 + j) * (SEQ * HID) + gcol];

    for (int t = 0; t < SEQ; ++t) {
        // ---- poll: 16 flags (bg, *) >= t+1 ----
        if (wave == 0) {
            int guard = 0;
            for (;;) {
                unsigned v = (lane < NCG) ? ld_ic(myfl + lane * FSTR) : 0xFFFFFFFFu;
                if (__all(v >= (unsigned)(t + 1))) break;
                if (++guard > (1 << 16)) break;   // degrade, never hang
                __builtin_amdgcn_s_sleep(1);
            }
        }
        __syncthreads();

        // ---- cooperative stage: A-stripe [16 rows][1024 k] -> LDS ----
        const unsigned short* src = (t & 1) ? hB : hA;
        bf16x8 st[8];
        int rws[8], kks[8];
        #pragma unroll
        for (int p = 0; p < 8; ++p) {
            int idx = tid + p * 256;               // 0..2047
            rws[p] = idx >> 7;
            kks[p] = (idx & 127) * 8;
            const unsigned short* sp =
                src + (size_t)(b0 + rws[p]) * HID + kks[p];
            asm volatile("global_load_dwordx4 %0, %1, off sc0 sc1"
                         : "=v"(st[p]) : "v"(sp) : "memory");
        }
        asm volatile("s_waitcnt vmcnt(0)" ::: "memory");
        #pragma unroll
        for (int p = 0; p < 8; ++p)
            *reinterpret_cast<bf16x8*>(&lds[rws[p] * 1032 + kks[p]]) = st[p];
        __syncthreads();

        // ---- fragments + MFMA (same accumulation order as R2/R6/R8) ----
        f32x4 ac0 = {}, ac1 = {}, ac2 = {}, ac3 = {};
        #pragma unroll
        for (int g = 0; g < 4; ++g) {
            bf16x8 Af[8];
            #pragma unroll
            for (int m = 0; m < 8; ++m)
                Af[m] = *reinterpret_cast<const bf16x8*>(
                    &lds[l15 * 1032 + (g * 8 + m) * 32 + kq8]);
            ac0 = __builtin_amdgcn_mfma_f32_16x16x32_bf16(Af[0], bfr[g*8+0], ac0, 0, 0, 0);
            ac1 = __builtin_amdgcn_mfma_f32_16x16x32_bf16(Af[1], bfr[g*8+1], ac1, 0, 0, 0);
            ac2 = __builtin_amdgcn_mfma_f32_16x16x32_bf16(Af[2], bfr[g*8+2], ac2, 0, 0, 0);
            ac3 = __builtin_amdgcn_mfma_f32_16x16x32_bf16(Af[3], bfr[g*8+3], ac3, 0, 0, 0);
            ac0 = __builtin_amdgcn_mfma_f32_16x16x32_bf16(Af[4], bfr[g*8+4], ac0, 0, 0, 0);
            ac1 = __builtin_amdgcn_mfma_f32_16x16x32_bf16(Af[5], bfr[g*8+5], ac1, 0, 0, 0);
            ac2 = __builtin_amdgcn_mfma_f32_16x16x32_bf16(Af[6], bfr[g*8+6], ac2, 0, 0, 0);
            ac3 = __builtin_amdgcn_mfma_f32_16x16x32_bf16(Af[7], bfr[g*8+7], ac3, 0, 0, 0);
        }
        f32x4 acc = (ac0 + ac1) + (ac2 + ac3);

        float hv[4];
        #pragma unroll
        for (int j = 0; j < 4; ++j)
            hv[j] = tanhf(acc[j] + xpv[j]);

        // ---- publish h_t slice via b64 exchanges, then flag ----
        if (t < SEQ - 1) {
            unsigned short* nxt = (t & 1) ? hA : hB;
            #pragma unroll
            for (int j = 0; j < 4; ++j) {
                unsigned u = (unsigned)f2bf(hv[j]);
                int base = lane & ~3;
                unsigned u0 = __shfl(u, base + 0);
                unsigned u1 = __shfl(u, base + 1);
                unsigned u2 = __shfl(u, base + 2);
                unsigned u3 = __shfl(u, base + 3);
                if ((lane & 3) == 0) {
                    unsigned long long d =  (unsigned long long)u0
                                         | ((unsigned long long)u1 << 16)
                                         | ((unsigned long long)u2 << 32)
                                         | ((unsigned long long)u3 << 48);
                    exch64((unsigned long long*)(nxt
                              + (size_t)(b0 + q4 + j) * HID
                              + c0 + wave * 16 + l15), d);
                }
            }
            asm volatile("s_waitcnt vmcnt(0)" ::: "memory");
            __syncthreads();
            if (tid == 0) exch32(flags + (bg * NCG + cg) * FSTR, (unsigned)(t + 2));
        }

        // ---- self-owned fp32 outputs + next xp prefetch ----
        #pragma unroll
        for (int j = 0; j < 4; ++j)
            out[(size_t)(b0 + q4 + j) * (SEQ * HID) + (size_t)t * HID + gcol] = hv[j];
        if (t == SEQ - 1) {
            #pragma unroll
            for (int j = 0; j < 4; ++j)
                out[(size_t)OUTSEQ_ELEMS + (size_t)(b0 + q4 + j) * HID + gcol] = hv[j];
        } else {
            #pragma unroll
            for (int j = 0; j < 4; ++j)
                xpv[j] = out[(size_t)(b0 + q4 + j) * (SEQ * HID)
                             + (size_t)(t + 1) * HID + gcol];
        }
    }
}

extern "C" void kernel_launch(void* const* d_in, const int* in_sizes, int n_in,
                              void* d_out, int out_size, void* d_ws, size_t ws_size,
                              hipStream_t stream)
{
    const float* input = (const float*)d_in[0];
    const float* h0    = (const float*)d_in[1];
    const float* W     = (const float*)d_in[2];
    const float* bias  = (const float*)d_in[3];
    float* out = (float*)d_out;

    unsigned short* hA = (unsigned short*)d_ws;
    unsigned short* hB = hA + (size_t)BATCH * HID;
    unsigned int* flags =
        (unsigned int*)((char*)d_ws + (size_t)2 * BATCH * HID * sizeof(unsigned short));

    dim3 gA(HID / 128, (BATCH * SEQ) / 128);   // (8, 256)
    xproj_gemm<<<gA, dim3(256), 0, stream>>>(input, W, bias, out);

    hipMemsetAsync(flags, 0, NBLK * FSTR * sizeof(unsigned int), stream);

    rnn_flow<<<dim3(NBLK), dim3(256), 0, stream>>>(W, h0, out, hA, hB, flags);
}

// Round 12
// 2612.989 us; speedup vs baseline: 2.3307x; 1.0602x over previous
//
#include <hip/hip_runtime.h>
#include <hip/hip_bf16.h>

#define BATCH 64
#define SEQ   512
#define ISZ   1024
#define HID   1024
#define OUTSEQ_ELEMS (BATCH * SEQ * HID)   // 33554432
#define NBG   4              // batch groups (16 batches each)
#define NCG   16             // col groups (64 cols each)
#define NBLK  (NBG * NCG)    // 64 blocks

typedef float f32x4 __attribute__((ext_vector_type(4)));
typedef short bf16x8 __attribute__((ext_vector_type(8)));
typedef unsigned u32x4 __attribute__((ext_vector_type(4)));

__device__ __forceinline__ unsigned short f2bf(float f) {
    union { float f; unsigned u; } v; v.f = f;
    unsigned r = v.u + 0x7fffu + ((v.u >> 16) & 1u);   // RNE
    return (unsigned short)(r >> 16);
}

// returning exchange: commits at the device coherence point (proven R8/R9)
__device__ __forceinline__ void exch64(unsigned long long* p, unsigned long long d) {
    unsigned long long old = __hip_atomic_exchange(p, d, __ATOMIC_RELAXED,
                                                   __HIP_MEMORY_SCOPE_AGENT);
    asm volatile("" :: "v"(old));
}

// ---------------------------------------------------------------------------
// Kernel A: xp[m][n] = input[m][:] . Wx[:][n] + b[n]  -> written into d_out.
// (unchanged since R1 — proven, ~180 us)
// ---------------------------------------------------------------------------
__global__ __launch_bounds__(256)
void xproj_gemm(const float* __restrict__ A, const float* __restrict__ W,
                const float* __restrict__ bias, float* __restrict__ C)
{
    __shared__ __align__(16) unsigned short As[128][72];
    __shared__ __align__(16) unsigned short Bs[128][72];
    const int tid  = threadIdx.x;
    const int lane = tid & 63;
    const int wave = tid >> 6;
    const int m0 = blockIdx.y * 128;
    const int n0 = blockIdx.x * 128;
    const int wm = (wave >> 1) * 64;
    const int wn = (wave & 1) * 64;
    const int l15 = lane & 15;
    const int kq8 = (lane >> 4) * 8;

    f32x4 acc[4][4] = {};

    for (int k0 = 0; k0 < ISZ; k0 += 64) {
        #pragma unroll
        for (int i = 0; i < 8; ++i) {
            int idx = tid + i * 256;
            int row = idx >> 4;
            int kq  = idx & 15;
            float4 v = *reinterpret_cast<const float4*>(
                A + (size_t)(m0 + row) * ISZ + k0 + kq * 4);
            unsigned short* dst = &As[row][kq * 4];
            dst[0] = f2bf(v.x); dst[1] = f2bf(v.y);
            dst[2] = f2bf(v.z); dst[3] = f2bf(v.w);
        }
        #pragma unroll
        for (int i = 0; i < 8; ++i) {
            int idx = tid + i * 256;
            int kk = idx >> 5;
            int nq = idx & 31;
            float4 v = *reinterpret_cast<const float4*>(
                W + (size_t)(k0 + kk) * HID + n0 + nq * 4);
            Bs[nq * 4 + 0][kk] = f2bf(v.x);
            Bs[nq * 4 + 1][kk] = f2bf(v.y);
            Bs[nq * 4 + 2][kk] = f2bf(v.z);
            Bs[nq * 4 + 3][kk] = f2bf(v.w);
        }
        __syncthreads();
        #pragma unroll
        for (int kk = 0; kk < 64; kk += 32) {
            const int krd = kk + kq8;
            bf16x8 a[4], b[4];
            #pragma unroll
            for (int mf = 0; mf < 4; ++mf)
                a[mf] = *reinterpret_cast<const bf16x8*>(&As[wm + mf * 16 + l15][krd]);
            #pragma unroll
            for (int nf = 0; nf < 4; ++nf)
                b[nf] = *reinterpret_cast<const bf16x8*>(&Bs[wn + nf * 16 + l15][krd]);
            #pragma unroll
            for (int mf = 0; mf < 4; ++mf)
                #pragma unroll
                for (int nf = 0; nf < 4; ++nf)
                    acc[mf][nf] = __builtin_amdgcn_mfma_f32_16x16x32_bf16(
                        a[mf], b[nf], acc[mf][nf], 0, 0, 0);
        }
        __syncthreads();
    }

    const int r4 = (lane >> 4) * 4;
    #pragma unroll
    for (int nf = 0; nf < 4; ++nf) {
        int col = n0 + wn + nf * 16 + l15;
        float bv = bias[col];
        #pragma unroll
        for (int mf = 0; mf < 4; ++mf) {
            int row = m0 + wm + mf * 16 + r4;
            #pragma unroll
            for (int r = 0; r < 4; ++r)
                C[(size_t)(row + r) * HID + col] = acc[mf][nf][r] + bv;
        }
    }
}

// ---------------------------------------------------------------------------
// Kernel B: flag-free dataflow RNN. h published as u32 (tag<<16 | bf16)
// via returning b64 exchanges into a double buffer; consumers read sc0sc1
// and verify tag==t per element, retrying while stale. Buffers memset to
// 0xFF pre-launch (in-graph) so no pre-existing word carries a valid tag.
// R12 fix: staging load row now includes b0 (R10/R11 read bg0's rows for
// every block — deterministic wrong values for bg>0).
// ---------------------------------------------------------------------------
__global__ __launch_bounds__(256, 1)
void rnn_flow(const float* __restrict__ W, const float* __restrict__ h0,
              float* __restrict__ out,
              unsigned* __restrict__ hb0, unsigned* __restrict__ hb1)
{
    __shared__ __align__(16) unsigned short lds[16 * 1032];   // 33 KB
    const int tid  = threadIdx.x;
    const int lane = tid & 63;
    const int wave = tid >> 6;              // col sub-tile
    const int bg = blockIdx.x >> 4;         // batch-group 0..3
    const int cg = blockIdx.x & 15;         // col-group 0..15
    const int b0 = bg * 16;
    const int c0 = cg * 64;
    const int l15 = lane & 15;
    const int kq8 = (lane >> 4) * 8;
    const int q4  = (lane >> 4) * 4;

    // ---- publish own h_0 slice with tag 0 ----
    {
        int row = tid >> 4;
        int c4  = (tid & 15) * 4;
        float4 v = *reinterpret_cast<const float4*>(
            h0 + (size_t)(b0 + row) * HID + c0 + c4);
        unsigned* base = hb0 + (size_t)(b0 + row) * HID + c0 + c4;
        exch64((unsigned long long*)base,
               (unsigned long long)(unsigned)f2bf(v.x)
             | ((unsigned long long)(unsigned)f2bf(v.y) << 32));
        exch64((unsigned long long*)(base + 2),
               (unsigned long long)(unsigned)f2bf(v.z)
             | ((unsigned long long)(unsigned)f2bf(v.w) << 32));
    }

    // ---- Wh cols [c0, c0+64) -> bfr (128 VGPR/lane), 4 LDS passes ----
    bf16x8 bfr[32];
    for (int w = 0; w < 4; ++w) {
        #pragma unroll 4
        for (int p = 0; p < 16; ++p) {
            int k  = p * 64 + (tid >> 2);
            int cc = (tid & 3) * 4;
            float4 v = *reinterpret_cast<const float4*>(
                W + (size_t)(ISZ + k) * HID + c0 + w * 16 + cc);
            lds[(cc + 0) * 1032 + k] = f2bf(v.x);
            lds[(cc + 1) * 1032 + k] = f2bf(v.y);
            lds[(cc + 2) * 1032 + k] = f2bf(v.z);
            lds[(cc + 3) * 1032 + k] = f2bf(v.w);
        }
        __syncthreads();
        if (wave == w) {
            #pragma unroll
            for (int ks = 0; ks < 32; ++ks)
                bfr[ks] = *reinterpret_cast<const bf16x8*>(
                    &lds[l15 * 1032 + ks * 32 + kq8]);
        }
        __syncthreads();
    }

    const int gcol = c0 + wave * 16 + l15;       // this lane's output column

    float xpv[4];
    #pragma unroll
    for (int j = 0; j < 4; ++j)
        xpv[j] = out[(size_t)(b0 + q4 + j) * (SEQ * HID) + gcol];

    for (int t = 0; t < SEQ; ++t) {
        // ---- stage A-stripe [16 rows][1024] from tagged u32 h, retry-fresh ----
        const unsigned* src = (t & 1) ? hb1 : hb0;
        const unsigned texp = (unsigned)t << 16;
        u32x4 q[16];
        int guard = 0;
        for (;;) {
            #pragma unroll
            for (int p = 0; p < 16; ++p) {
                int idx = tid + p * 256;
                const unsigned* sp = src + (size_t)(b0 + (idx >> 8)) * HID
                                         + (idx & 255) * 4;    // R12: +b0 fix
                asm volatile("global_load_dwordx4 %0, %1, off sc0 sc1"
                             : "=v"(q[p]) : "v"(sp) : "memory");
            }
            asm volatile("s_waitcnt vmcnt(0)" ::: "memory");
            unsigned bad = 0;
            #pragma unroll
            for (int p = 0; p < 16; ++p) {
                bad |= (q[p][0] ^ texp);
                bad |= (q[p][1] ^ texp);
                bad |= (q[p][2] ^ texp);
                bad |= (q[p][3] ^ texp);
            }
            if (!__any((bad & 0xFFFF0000u) != 0)) break;
            if (++guard > (1 << 14)) break;   // degrade, never hang
        }
        #pragma unroll
        for (int p = 0; p < 16; ++p) {
            int idx = tid + p * 256;
            int row = idx >> 8;
            int cq  = (idx & 255) * 4;
            unsigned long long d =
                  (unsigned long long)(q[p][0] & 0xFFFFu)
                | ((unsigned long long)(q[p][1] & 0xFFFFu) << 16)
                | ((unsigned long long)(q[p][2] & 0xFFFFu) << 32)
                | ((unsigned long long)(q[p][3] & 0xFFFFu) << 48);
            *reinterpret_cast<unsigned long long*>(&lds[row * 1032 + cq]) = d;
        }
        __syncthreads();

        // ---- fragments + MFMA (accumulation order unchanged) ----
        f32x4 ac0 = {}, ac1 = {}, ac2 = {}, ac3 = {};
        #pragma unroll
        for (int g = 0; g < 4; ++g) {
            bf16x8 Af[8];
            #pragma unroll
            for (int m = 0; m < 8; ++m)
                Af[m] = *reinterpret_cast<const bf16x8*>(
                    &lds[l15 * 1032 + (g * 8 + m) * 32 + kq8]);
            ac0 = __builtin_amdgcn_mfma_f32_16x16x32_bf16(Af[0], bfr[g*8+0], ac0, 0, 0, 0);
            ac1 = __builtin_amdgcn_mfma_f32_16x16x32_bf16(Af[1], bfr[g*8+1], ac1, 0, 0, 0);
            ac2 = __builtin_amdgcn_mfma_f32_16x16x32_bf16(Af[2], bfr[g*8+2], ac2, 0, 0, 0);
            ac3 = __builtin_amdgcn_mfma_f32_16x16x32_bf16(Af[3], bfr[g*8+3], ac3, 0, 0, 0);
            ac0 = __builtin_amdgcn_mfma_f32_16x16x32_bf16(Af[4], bfr[g*8+4], ac0, 0, 0, 0);
            ac1 = __builtin_amdgcn_mfma_f32_16x16x32_bf16(Af[5], bfr[g*8+5], ac1, 0, 0, 0);
            ac2 = __builtin_amdgcn_mfma_f32_16x16x32_bf16(Af[6], bfr[g*8+6], ac2, 0, 0, 0);
            ac3 = __builtin_amdgcn_mfma_f32_16x16x32_bf16(Af[7], bfr[g*8+7], ac3, 0, 0, 0);
        }
        __syncthreads();   // frag reads done before next iteration's LDS write
        f32x4 acc = (ac0 + ac1) + (ac2 + ac3);

        float hv[4];
        #pragma unroll
        for (int j = 0; j < 4; ++j)
            hv[j] = tanhf(acc[j] + xpv[j]);

        // ---- publish h_t (tag t+1) via b64 exchanges — no drain, no flag ----
        if (t < SEQ - 1) {
            unsigned* dst = (t & 1) ? hb0 : hb1;        // hb[(t+1)&1]
            const unsigned tagv = (unsigned)(t + 1) << 16;
            #pragma unroll
            for (int j = 0; j < 4; ++j) {
                unsigned e  = tagv | (unsigned)f2bf(hv[j]);
                unsigned pe = __shfl(e, lane | 1);      // partner (odd lane) elem
                if ((lane & 1) == 0) {
                    unsigned long long d = (unsigned long long)e
                                         | ((unsigned long long)pe << 32);
                    exch64((unsigned long long*)(dst
                              + (size_t)(b0 + q4 + j) * HID + gcol), d);
                }
            }
        }

        // ---- self-owned fp32 outputs + next xp prefetch ----
        #pragma unroll
        for (int j = 0; j < 4; ++j)
            out[(size_t)(b0 + q4 + j) * (SEQ * HID) + (size_t)t * HID + gcol] = hv[j];
        if (t == SEQ - 1) {
            #pragma unroll
            for (int j = 0; j < 4; ++j)
                out[(size_t)OUTSEQ_ELEMS + (size_t)(b0 + q4 + j) * HID + gcol] = hv[j];
        } else {
            #pragma unroll
            for (int j = 0; j < 4; ++j)
                xpv[j] = out[(size_t)(b0 + q4 + j) * (SEQ * HID)
                             + (size_t)(t + 1) * HID + gcol];
        }
    }
}

extern "C" void kernel_launch(void* const* d_in, const int* in_sizes, int n_in,
                              void* d_out, int out_size, void* d_ws, size_t ws_size,
                              hipStream_t stream)
{
    const float* input = (const float*)d_in[0];
    const float* h0    = (const float*)d_in[1];
    const float* W     = (const float*)d_in[2];
    const float* bias  = (const float*)d_in[3];
    float* out = (float*)d_out;

    unsigned* hb0 = (unsigned*)d_ws;                       // 256 KB
    unsigned* hb1 = hb0 + (size_t)BATCH * HID;             // 256 KB

    // Wipe tag space (0xFFFF never equals a valid tag 0..511). In-graph,
    // so every replay self-cleans; required for the first un-poisoned launch.
    hipMemsetAsync(d_ws, 0xFF, (size_t)2 * BATCH * HID * sizeof(unsigned), stream);

    dim3 gA(HID / 128, (BATCH * SEQ) / 128);   // (8, 256)
    xproj_gemm<<<gA, dim3(256), 0, stream>>>(input, W, bias, out);

    rnn_flow<<<dim3(NBLK), dim3(256), 0, stream>>>(W, h0, out, hb0, hb1);
}

// Round 13
// 2264.109 us; speedup vs baseline: 2.6899x; 1.1541x over previous
//
#include <hip/hip_runtime.h>
#include <hip/hip_bf16.h>

#define BATCH 64
#define SEQ   512
#define ISZ   1024
#define HID   1024
#define OUTSEQ_ELEMS (BATCH * SEQ * HID)   // 33554432
#define NBG   4              // batch groups (16 batches each)
#define NCG   16             // col groups (64 cols each)
#define NBLK  (NBG * NCG)    // 64 blocks

typedef float f32x4 __attribute__((ext_vector_type(4)));
typedef short bf16x8 __attribute__((ext_vector_type(8)));
typedef unsigned u32x4 __attribute__((ext_vector_type(4)));

__device__ __forceinline__ unsigned short f2bf(float f) {
    union { float f; unsigned u; } v; v.f = f;
    unsigned r = v.u + 0x7fffu + ((v.u >> 16) & 1u);   // RNE
    return (unsigned short)(r >> 16);
}

// ---------------------------------------------------------------------------
// Kernel A: xp[m][n] = input[m][:] . Wx[:][n] + b[n]  -> written into d_out.
// (unchanged since R1 — proven, ~180 us)
// ---------------------------------------------------------------------------
__global__ __launch_bounds__(256)
void xproj_gemm(const float* __restrict__ A, const float* __restrict__ W,
                const float* __restrict__ bias, float* __restrict__ C)
{
    __shared__ __align__(16) unsigned short As[128][72];
    __shared__ __align__(16) unsigned short Bs[128][72];
    const int tid  = threadIdx.x;
    const int lane = tid & 63;
    const int wave = tid >> 6;
    const int m0 = blockIdx.y * 128;
    const int n0 = blockIdx.x * 128;
    const int wm = (wave >> 1) * 64;
    const int wn = (wave & 1) * 64;
    const int l15 = lane & 15;
    const int kq8 = (lane >> 4) * 8;

    f32x4 acc[4][4] = {};

    for (int k0 = 0; k0 < ISZ; k0 += 64) {
        #pragma unroll
        for (int i = 0; i < 8; ++i) {
            int idx = tid + i * 256;
            int row = idx >> 4;
            int kq  = idx & 15;
            float4 v = *reinterpret_cast<const float4*>(
                A + (size_t)(m0 + row) * ISZ + k0 + kq * 4);
            unsigned short* dst = &As[row][kq * 4];
            dst[0] = f2bf(v.x); dst[1] = f2bf(v.y);
            dst[2] = f2bf(v.z); dst[3] = f2bf(v.w);
        }
        #pragma unroll
        for (int i = 0; i < 8; ++i) {
            int idx = tid + i * 256;
            int kk = idx >> 5;
            int nq = idx & 31;
            float4 v = *reinterpret_cast<const float4*>(
                W + (size_t)(k0 + kk) * HID + n0 + nq * 4);
            Bs[nq * 4 + 0][kk] = f2bf(v.x);
            Bs[nq * 4 + 1][kk] = f2bf(v.y);
            Bs[nq * 4 + 2][kk] = f2bf(v.z);
            Bs[nq * 4 + 3][kk] = f2bf(v.w);
        }
        __syncthreads();
        #pragma unroll
        for (int kk = 0; kk < 64; kk += 32) {
            const int krd = kk + kq8;
            bf16x8 a[4], b[4];
            #pragma unroll
            for (int mf = 0; mf < 4; ++mf)
                a[mf] = *reinterpret_cast<const bf16x8*>(&As[wm + mf * 16 + l15][krd]);
            #pragma unroll
            for (int nf = 0; nf < 4; ++nf)
                b[nf] = *reinterpret_cast<const bf16x8*>(&Bs[wn + nf * 16 + l15][krd]);
            #pragma unroll
            for (int mf = 0; mf < 4; ++mf)
                #pragma unroll
                for (int nf = 0; nf < 4; ++nf)
                    acc[mf][nf] = __builtin_amdgcn_mfma_f32_16x16x32_bf16(
                        a[mf], b[nf], acc[mf][nf], 0, 0, 0);
        }
        __syncthreads();
    }

    const int r4 = (lane >> 4) * 4;
    #pragma unroll
    for (int nf = 0; nf < 4; ++nf) {
        int col = n0 + wn + nf * 16 + l15;
        float bv = bias[col];
        #pragma unroll
        for (int mf = 0; mf < 4; ++mf) {
            int row = m0 + wm + mf * 16 + r4;
            #pragma unroll
            for (int r = 0; r < 4; ++r)
                C[(size_t)(row + r) * HID + col] = acc[mf][nf][r] + bv;
        }
    }
}

// ---------------------------------------------------------------------------
// Kernel B: flag-free tagged-dataflow RNN (R12 protocol, proven).
// R13 changes (latency/retry tuning, protocol unchanged):
//   - selective retry: re-read only stale quads (16-bit mask per thread)
//   - early issue: next step's stage loads fired right after the publish
//     stores; out-stores/xp-prefetch overlap the flight
//   - publish via plain sc0 sc1 write-through stores (tags make per-dword
//     atomicity sufficient; no RMW serialization at the IC)
//   - LDS stripe double-buffered -> one __syncthreads per step
// ---------------------------------------------------------------------------
__global__ __launch_bounds__(256, 1)
void rnn_flow(const float* __restrict__ W, const float* __restrict__ h0,
              float* __restrict__ out,
              unsigned* __restrict__ hb0, unsigned* __restrict__ hb1)
{
    __shared__ __align__(16) unsigned short lds[2][16 * 1032];   // 66 KB
    const int tid  = threadIdx.x;
    const int lane = tid & 63;
    const int wave = tid >> 6;              // col sub-tile
    const int bg = blockIdx.x >> 4;         // batch-group 0..3
    const int cg = blockIdx.x & 15;         // col-group 0..15
    const int b0 = bg * 16;
    const int c0 = cg * 64;
    const int l15 = lane & 15;
    const int kq8 = (lane >> 4) * 8;
    const int q4  = (lane >> 4) * 4;

    // ---- publish own h_0 slice with tag 0 (plain write-through) ----
    {
        int row = tid >> 4;
        int c4  = (tid & 15) * 4;
        float4 v = *reinterpret_cast<const float4*>(
            h0 + (size_t)(b0 + row) * HID + c0 + c4);
        u32x4 d;
        d[0] = (unsigned)f2bf(v.x); d[1] = (unsigned)f2bf(v.y);
        d[2] = (unsigned)f2bf(v.z); d[3] = (unsigned)f2bf(v.w);
        unsigned* p = hb0 + (size_t)(b0 + row) * HID + c0 + c4;
        asm volatile("global_store_dwordx4 %0, %1, off sc0 sc1"
                     :: "v"(p), "v"(d) : "memory");
    }

    // ---- Wh cols [c0, c0+64) -> bfr (128 VGPR/lane), 4 LDS passes ----
    bf16x8 bfr[32];
    {
        unsigned short* l0 = &lds[0][0];
        for (int w = 0; w < 4; ++w) {
            #pragma unroll 4
            for (int p = 0; p < 16; ++p) {
                int k  = p * 64 + (tid >> 2);
                int cc = (tid & 3) * 4;
                float4 v = *reinterpret_cast<const float4*>(
                    W + (size_t)(ISZ + k) * HID + c0 + w * 16 + cc);
                l0[(cc + 0) * 1032 + k] = f2bf(v.x);
                l0[(cc + 1) * 1032 + k] = f2bf(v.y);
                l0[(cc + 2) * 1032 + k] = f2bf(v.z);
                l0[(cc + 3) * 1032 + k] = f2bf(v.w);
            }
            __syncthreads();
            if (wave == w) {
                #pragma unroll
                for (int ks = 0; ks < 32; ++ks)
                    bfr[ks] = *reinterpret_cast<const bf16x8*>(
                        &l0[l15 * 1032 + ks * 32 + kq8]);
            }
            __syncthreads();
        }
    }

    const int gcol = c0 + wave * 16 + l15;       // this lane's output column

    float xpv[4];
    #pragma unroll
    for (int j = 0; j < 4; ++j)
        xpv[j] = out[(size_t)(b0 + q4 + j) * (SEQ * HID) + gcol];

    // ---- issue initial stage loads (t=0): row p, col-quad tid*4 ----
    u32x4 q[16];
    #pragma unroll
    for (int p = 0; p < 16; ++p) {
        const unsigned* sp = hb0 + (size_t)(b0 + p) * HID + tid * 4;
        asm volatile("global_load_dwordx4 %0, %1, off sc0 sc1"
                     : "=v"(q[p]) : "v"(sp) : "memory");
    }

    for (int t = 0; t < SEQ; ++t) {
        const unsigned* src = (t & 1) ? hb1 : hb0;
        const unsigned texp = (unsigned)t << 16;

        // ---- drain early-issued loads, then selective retry on stale quads ----
        asm volatile("s_waitcnt vmcnt(0)" ::: "memory");
        unsigned stale = 0;
        #pragma unroll
        for (int p = 0; p < 16; ++p) {
            unsigned bad = (q[p][0] ^ texp) | (q[p][1] ^ texp)
                         | (q[p][2] ^ texp) | (q[p][3] ^ texp);
            if (bad & 0xFFFF0000u) stale |= (1u << p);
        }
        int guard = 0;
        while (stale) {
            #pragma unroll
            for (int p = 0; p < 16; ++p) {
                if (stale & (1u << p)) {
                    const unsigned* sp = src + (size_t)(b0 + p) * HID + tid * 4;
                    asm volatile("global_load_dwordx4 %0, %1, off sc0 sc1"
                                 : "=v"(q[p]) : "v"(sp) : "memory");
                }
            }
            asm volatile("s_waitcnt vmcnt(0)" ::: "memory");
            unsigned ns = 0;
            #pragma unroll
            for (int p = 0; p < 16; ++p) {
                if (stale & (1u << p)) {
                    unsigned bad = (q[p][0] ^ texp) | (q[p][1] ^ texp)
                                 | (q[p][2] ^ texp) | (q[p][3] ^ texp);
                    if (bad & 0xFFFF0000u) ns |= (1u << p);
                }
            }
            stale = ns;
            if (++guard > (1 << 14)) break;   // degrade, never hang
        }

        // ---- strip tags -> LDS[t&1] (row p, col-quad tid*4) ----
        unsigned short* lb = &lds[t & 1][0];
        #pragma unroll
        for (int p = 0; p < 16; ++p) {
            unsigned long long d =
                  (unsigned long long)(q[p][0] & 0xFFFFu)
                | ((unsigned long long)(q[p][1] & 0xFFFFu) << 16)
                | ((unsigned long long)(q[p][2] & 0xFFFFu) << 32)
                | ((unsigned long long)(q[p][3] & 0xFFFFu) << 48);
            *reinterpret_cast<unsigned long long*>(&lb[p * 1032 + tid * 4]) = d;
        }
        __syncthreads();   // single barrier per step (LDS double-buffered)

        // ---- fragments + MFMA (accumulation order unchanged) ----
        f32x4 ac0 = {}, ac1 = {}, ac2 = {}, ac3 = {};
        #pragma unroll
        for (int g = 0; g < 4; ++g) {
            bf16x8 Af[8];
            #pragma unroll
            for (int m = 0; m < 8; ++m)
                Af[m] = *reinterpret_cast<const bf16x8*>(
                    &lb[l15 * 1032 + (g * 8 + m) * 32 + kq8]);
            ac0 = __builtin_amdgcn_mfma_f32_16x16x32_bf16(Af[0], bfr[g*8+0], ac0, 0, 0, 0);
            ac1 = __builtin_amdgcn_mfma_f32_16x16x32_bf16(Af[1], bfr[g*8+1], ac1, 0, 0, 0);
            ac2 = __builtin_amdgcn_mfma_f32_16x16x32_bf16(Af[2], bfr[g*8+2], ac2, 0, 0, 0);
            ac3 = __builtin_amdgcn_mfma_f32_16x16x32_bf16(Af[3], bfr[g*8+3], ac3, 0, 0, 0);
            ac0 = __builtin_amdgcn_mfma_f32_16x16x32_bf16(Af[4], bfr[g*8+4], ac0, 0, 0, 0);
            ac1 = __builtin_amdgcn_mfma_f32_16x16x32_bf16(Af[5], bfr[g*8+5], ac1, 0, 0, 0);
            ac2 = __builtin_amdgcn_mfma_f32_16x16x32_bf16(Af[6], bfr[g*8+6], ac2, 0, 0, 0);
            ac3 = __builtin_amdgcn_mfma_f32_16x16x32_bf16(Af[7], bfr[g*8+7], ac3, 0, 0, 0);
        }
        f32x4 acc = (ac0 + ac1) + (ac2 + ac3);

        float hv[4];
        #pragma unroll
        for (int j = 0; j < 4; ++j)
            hv[j] = tanhf(acc[j] + xpv[j]);

        if (t < SEQ - 1) {
            // ---- publish h_t (tag t+1): plain write-through, pair-packed ----
            unsigned* dst = (t & 1) ? hb0 : hb1;        // hb[(t+1)&1]
            const unsigned tagv = (unsigned)(t + 1) << 16;
            #pragma unroll
            for (int j = 0; j < 4; ++j) {
                unsigned e  = tagv | (unsigned)f2bf(hv[j]);
                unsigned pe = __shfl(e, lane | 1);      // partner (odd lane) elem
                if ((lane & 1) == 0) {
                    unsigned long long d = (unsigned long long)e
                                         | ((unsigned long long)pe << 32);
                    unsigned* p = dst + (size_t)(b0 + q4 + j) * HID + gcol;
                    asm volatile("global_store_dwordx2 %0, %1, off sc0 sc1"
                                 :: "v"(p), "v"(d) : "memory");
                }
            }
            // ---- early-issue next step's stage loads (overlap out stores) ----
            #pragma unroll
            for (int p = 0; p < 16; ++p) {
                const unsigned* sp = dst + (size_t)(b0 + p) * HID + tid * 4;
                asm volatile("global_load_dwordx4 %0, %1, off sc0 sc1"
                             : "=v"(q[p]) : "v"(sp) : "memory");
            }
        }

        // ---- self-owned fp32 outputs + next xp prefetch ----
        #pragma unroll
        for (int j = 0; j < 4; ++j)
            out[(size_t)(b0 + q4 + j) * (SEQ * HID) + (size_t)t * HID + gcol] = hv[j];
        if (t == SEQ - 1) {
            #pragma unroll
            for (int j = 0; j < 4; ++j)
                out[(size_t)OUTSEQ_ELEMS + (size_t)(b0 + q4 + j) * HID + gcol] = hv[j];
        } else {
            #pragma unroll
            for (int j = 0; j < 4; ++j)
                xpv[j] = out[(size_t)(b0 + q4 + j) * (SEQ * HID)
                             + (size_t)(t + 1) * HID + gcol];
        }
    }
}

extern "C" void kernel_launch(void* const* d_in, const int* in_sizes, int n_in,
                              void* d_out, int out_size, void* d_ws, size_t ws_size,
                              hipStream_t stream)
{
    const float* input = (const float*)d_in[0];
    const float* h0    = (const float*)d_in[1];
    const float* W     = (const float*)d_in[2];
    const float* bias  = (const float*)d_in[3];
    float* out = (float*)d_out;

    unsigned* hb0 = (unsigned*)d_ws;                       // 256 KB
    unsigned* hb1 = hb0 + (size_t)BATCH * HID;             // 256 KB

    // Wipe tag space (0xFFFF never equals a valid tag 0..511). In-graph,
    // so every replay self-cleans; required for the first un-poisoned launch.
    hipMemsetAsync(d_ws, 0xFF, (size_t)2 * BATCH * HID * sizeof(unsigned), stream);

    dim3 gA(HID / 128, (BATCH * SEQ) / 128);   // (8, 256)
    xproj_gemm<<<gA, dim3(256), 0, stream>>>(input, W, bias, out);

    rnn_flow<<<dim3(NBLK), dim3(256), 0, stream>>>(W, h0, out, hb0, hb1);
}

// Round 14
// 2204.761 us; speedup vs baseline: 2.7623x; 1.0269x over previous
//
#include <hip/hip_runtime.h>
#include <hip/hip_bf16.h>

#define BATCH 64
#define SEQ   512
#define ISZ   1024
#define HID   1024
#define OUTSEQ_ELEMS (BATCH * SEQ * HID)   // 33554432
#define NBG   4              // batch groups (16 batches each)
#define NCG   16             // col groups (64 cols each)
#define NBLK  (NBG * NCG)    // 64 blocks

typedef float f32x4 __attribute__((ext_vector_type(4)));
typedef short bf16x8 __attribute__((ext_vector_type(8)));
typedef unsigned u32x4 __attribute__((ext_vector_type(4)));

__device__ __forceinline__ unsigned short f2bf(float f) {
    union { float f; unsigned u; } v; v.f = f;
    unsigned r = v.u + 0x7fffu + ((v.u >> 16) & 1u);   // RNE
    return (unsigned short)(r >> 16);
}

// ---------------------------------------------------------------------------
// Kernel A: xp[m][n] = input[m][:] . Wx[:][n] + b[n]  -> written into d_out.
// (unchanged since R1 — proven, ~180 us)
// ---------------------------------------------------------------------------
__global__ __launch_bounds__(256)
void xproj_gemm(const float* __restrict__ A, const float* __restrict__ W,
                const float* __restrict__ bias, float* __restrict__ C)
{
    __shared__ __align__(16) unsigned short As[128][72];
    __shared__ __align__(16) unsigned short Bs[128][72];
    const int tid  = threadIdx.x;
    const int lane = tid & 63;
    const int wave = tid >> 6;
    const int m0 = blockIdx.y * 128;
    const int n0 = blockIdx.x * 128;
    const int wm = (wave >> 1) * 64;
    const int wn = (wave & 1) * 64;
    const int l15 = lane & 15;
    const int kq8 = (lane >> 4) * 8;

    f32x4 acc[4][4] = {};

    for (int k0 = 0; k0 < ISZ; k0 += 64) {
        #pragma unroll
        for (int i = 0; i < 8; ++i) {
            int idx = tid + i * 256;
            int row = idx >> 4;
            int kq  = idx & 15;
            float4 v = *reinterpret_cast<const float4*>(
                A + (size_t)(m0 + row) * ISZ + k0 + kq * 4);
            unsigned short* dst = &As[row][kq * 4];
            dst[0] = f2bf(v.x); dst[1] = f2bf(v.y);
            dst[2] = f2bf(v.z); dst[3] = f2bf(v.w);
        }
        #pragma unroll
        for (int i = 0; i < 8; ++i) {
            int idx = tid + i * 256;
            int kk = idx >> 5;
            int nq = idx & 31;
            float4 v = *reinterpret_cast<const float4*>(
                W + (size_t)(k0 + kk) * HID + n0 + nq * 4);
            Bs[nq * 4 + 0][kk] = f2bf(v.x);
            Bs[nq * 4 + 1][kk] = f2bf(v.y);
            Bs[nq * 4 + 2][kk] = f2bf(v.z);
            Bs[nq * 4 + 3][kk] = f2bf(v.w);
        }
        __syncthreads();
        #pragma unroll
        for (int kk = 0; kk < 64; kk += 32) {
            const int krd = kk + kq8;
            bf16x8 a[4], b[4];
            #pragma unroll
            for (int mf = 0; mf < 4; ++mf)
                a[mf] = *reinterpret_cast<const bf16x8*>(&As[wm + mf * 16 + l15][krd]);
            #pragma unroll
            for (int nf = 0; nf < 4; ++nf)
                b[nf] = *reinterpret_cast<const bf16x8*>(&Bs[wn + nf * 16 + l15][krd]);
            #pragma unroll
            for (int mf = 0; mf < 4; ++mf)
                #pragma unroll
                for (int nf = 0; nf < 4; ++nf)
                    acc[mf][nf] = __builtin_amdgcn_mfma_f32_16x16x32_bf16(
                        a[mf], b[nf], acc[mf][nf], 0, 0, 0);
        }
        __syncthreads();
    }

    const int r4 = (lane >> 4) * 4;
    #pragma unroll
    for (int nf = 0; nf < 4; ++nf) {
        int col = n0 + wn + nf * 16 + l15;
        float bv = bias[col];
        #pragma unroll
        for (int mf = 0; mf < 4; ++mf) {
            int row = m0 + wm + mf * 16 + r4;
            #pragma unroll
            for (int r = 0; r < 4; ++r)
                C[(size_t)(row + r) * HID + col] = acc[mf][nf][r] + bv;
        }
    }
}

// ---------------------------------------------------------------------------
// Kernel B: flag-free tagged-dataflow RNN (R12/R13 protocol, proven).
// R14 changes (cache-policy + scheduling only, protocol untouched):
//   - out stores / xp loads: PLAIN cached (region is block-self-owned;
//     R6's sc0sc1 write-through caused per-dword RFO line-fetches = the
//     ~430 MB of unexplained FETCH_SIZE and IC store-ack stalls)
//   - xp[t+1] prefetch issued right after __syncthreads (hides under the
//     MFMA phase instead of extending the next drain)
// ---------------------------------------------------------------------------
__global__ __launch_bounds__(256, 1)
void rnn_flow(const float* __restrict__ W, const float* __restrict__ h0,
              float* __restrict__ out,
              unsigned* __restrict__ hb0, unsigned* __restrict__ hb1)
{
    __shared__ __align__(16) unsigned short lds[2][16 * 1032];   // 66 KB
    const int tid  = threadIdx.x;
    const int lane = tid & 63;
    const int wave = tid >> 6;              // col sub-tile
    const int bg = blockIdx.x >> 4;         // batch-group 0..3
    const int cg = blockIdx.x & 15;         // col-group 0..15
    const int b0 = bg * 16;
    const int c0 = cg * 64;
    const int l15 = lane & 15;
    const int kq8 = (lane >> 4) * 8;
    const int q4  = (lane >> 4) * 4;

    // ---- publish own h_0 slice with tag 0 (write-through) ----
    {
        int row = tid >> 4;
        int c4  = (tid & 15) * 4;
        float4 v = *reinterpret_cast<const float4*>(
            h0 + (size_t)(b0 + row) * HID + c0 + c4);
        u32x4 d;
        d[0] = (unsigned)f2bf(v.x); d[1] = (unsigned)f2bf(v.y);
        d[2] = (unsigned)f2bf(v.z); d[3] = (unsigned)f2bf(v.w);
        unsigned* p = hb0 + (size_t)(b0 + row) * HID + c0 + c4;
        asm volatile("global_store_dwordx4 %0, %1, off sc0 sc1"
                     :: "v"(p), "v"(d) : "memory");
    }

    // ---- Wh cols [c0, c0+64) -> bfr (128 VGPR/lane), 4 LDS passes ----
    bf16x8 bfr[32];
    {
        unsigned short* l0 = &lds[0][0];
        for (int w = 0; w < 4; ++w) {
            #pragma unroll 4
            for (int p = 0; p < 16; ++p) {
                int k  = p * 64 + (tid >> 2);
                int cc = (tid & 3) * 4;
                float4 v = *reinterpret_cast<const float4*>(
                    W + (size_t)(ISZ + k) * HID + c0 + w * 16 + cc);
                l0[(cc + 0) * 1032 + k] = f2bf(v.x);
                l0[(cc + 1) * 1032 + k] = f2bf(v.y);
                l0[(cc + 2) * 1032 + k] = f2bf(v.z);
                l0[(cc + 3) * 1032 + k] = f2bf(v.w);
            }
            __syncthreads();
            if (wave == w) {
                #pragma unroll
                for (int ks = 0; ks < 32; ++ks)
                    bfr[ks] = *reinterpret_cast<const bf16x8*>(
                        &l0[l15 * 1032 + ks * 32 + kq8]);
            }
            __syncthreads();
        }
    }

    const int gcol = c0 + wave * 16 + l15;       // this lane's output column

    float xpv[4];
    #pragma unroll
    for (int j = 0; j < 4; ++j)
        xpv[j] = out[(size_t)(b0 + q4 + j) * (SEQ * HID) + gcol];

    // ---- issue initial stage loads (t=0): row p, col-quad tid*4 ----
    u32x4 q[16];
    #pragma unroll
    for (int p = 0; p < 16; ++p) {
        const unsigned* sp = hb0 + (size_t)(b0 + p) * HID + tid * 4;
        asm volatile("global_load_dwordx4 %0, %1, off sc0 sc1"
                     : "=v"(q[p]) : "v"(sp) : "memory");
    }

    for (int t = 0; t < SEQ; ++t) {
        const unsigned* src = (t & 1) ? hb1 : hb0;
        const unsigned texp = (unsigned)t << 16;

        // ---- drain early-issued loads, then selective retry on stale quads ----
        asm volatile("s_waitcnt vmcnt(0)" ::: "memory");
        unsigned stale = 0;
        #pragma unroll
        for (int p = 0; p < 16; ++p) {
            unsigned bad = (q[p][0] ^ texp) | (q[p][1] ^ texp)
                         | (q[p][2] ^ texp) | (q[p][3] ^ texp);
            if (bad & 0xFFFF0000u) stale |= (1u << p);
        }
        int guard = 0;
        while (stale) {
            #pragma unroll
            for (int p = 0; p < 16; ++p) {
                if (stale & (1u << p)) {
                    const unsigned* sp = src + (size_t)(b0 + p) * HID + tid * 4;
                    asm volatile("global_load_dwordx4 %0, %1, off sc0 sc1"
                                 : "=v"(q[p]) : "v"(sp) : "memory");
                }
            }
            asm volatile("s_waitcnt vmcnt(0)" ::: "memory");
            unsigned ns = 0;
            #pragma unroll
            for (int p = 0; p < 16; ++p) {
                if (stale & (1u << p)) {
                    unsigned bad = (q[p][0] ^ texp) | (q[p][1] ^ texp)
                                 | (q[p][2] ^ texp) | (q[p][3] ^ texp);
                    if (bad & 0xFFFF0000u) ns |= (1u << p);
                }
            }
            stale = ns;
            if (++guard > (1 << 14)) break;   // degrade, never hang
        }

        // ---- strip tags -> LDS[t&1] (row p, col-quad tid*4) ----
        unsigned short* lb = &lds[t & 1][0];
        #pragma unroll
        for (int p = 0; p < 16; ++p) {
            unsigned long long d =
                  (unsigned long long)(q[p][0] & 0xFFFFu)
                | ((unsigned long long)(q[p][1] & 0xFFFFu) << 16)
                | ((unsigned long long)(q[p][2] & 0xFFFFu) << 32)
                | ((unsigned long long)(q[p][3] & 0xFFFFu) << 48);
            *reinterpret_cast<unsigned long long*>(&lb[p * 1032 + tid * 4]) = d;
        }
        __syncthreads();   // single barrier per step (LDS double-buffered)

        // ---- prefetch xp[t+1] NOW (plain cached; hides under MFMA phase) ----
        float xpn[4];
        if (t < SEQ - 1) {
            #pragma unroll
            for (int j = 0; j < 4; ++j)
                xpn[j] = out[(size_t)(b0 + q4 + j) * (SEQ * HID)
                             + (size_t)(t + 1) * HID + gcol];
        }

        // ---- fragments + MFMA (accumulation order unchanged) ----
        f32x4 ac0 = {}, ac1 = {}, ac2 = {}, ac3 = {};
        #pragma unroll
        for (int g = 0; g < 4; ++g) {
            bf16x8 Af[8];
            #pragma unroll
            for (int m = 0; m < 8; ++m)
                Af[m] = *reinterpret_cast<const bf16x8*>(
                    &lb[l15 * 1032 + (g * 8 + m) * 32 + kq8]);
            ac0 = __builtin_amdgcn_mfma_f32_16x16x32_bf16(Af[0], bfr[g*8+0], ac0, 0, 0, 0);
            ac1 = __builtin_amdgcn_mfma_f32_16x16x32_bf16(Af[1], bfr[g*8+1], ac1, 0, 0, 0);
            ac2 = __builtin_amdgcn_mfma_f32_16x16x32_bf16(Af[2], bfr[g*8+2], ac2, 0, 0, 0);
            ac3 = __builtin_amdgcn_mfma_f32_16x16x32_bf16(Af[3], bfr[g*8+3], ac3, 0, 0, 0);
            ac0 = __builtin_amdgcn_mfma_f32_16x16x32_bf16(Af[4], bfr[g*8+4], ac0, 0, 0, 0);
            ac1 = __builtin_amdgcn_mfma_f32_16x16x32_bf16(Af[5], bfr[g*8+5], ac1, 0, 0, 0);
            ac2 = __builtin_amdgcn_mfma_f32_16x16x32_bf16(Af[6], bfr[g*8+6], ac2, 0, 0, 0);
            ac3 = __builtin_amdgcn_mfma_f32_16x16x32_bf16(Af[7], bfr[g*8+7], ac3, 0, 0, 0);
        }
        f32x4 acc = (ac0 + ac1) + (ac2 + ac3);

        float hv[4];
        #pragma unroll
        for (int j = 0; j < 4; ++j)
            hv[j] = tanhf(acc[j] + xpv[j]);

        if (t < SEQ - 1) {
            // ---- publish h_t (tag t+1): write-through, pair-packed ----
            unsigned* dst = (t & 1) ? hb0 : hb1;        // hb[(t+1)&1]
            const unsigned tagv = (unsigned)(t + 1) << 16;
            #pragma unroll
            for (int j = 0; j < 4; ++j) {
                unsigned e  = tagv | (unsigned)f2bf(hv[j]);
                unsigned pe = __shfl(e, lane | 1);      // partner (odd lane) elem
                if ((lane & 1) == 0) {
                    unsigned long long d = (unsigned long long)e
                                         | ((unsigned long long)pe << 32);
                    unsigned* p = dst + (size_t)(b0 + q4 + j) * HID + gcol;
                    asm volatile("global_store_dwordx2 %0, %1, off sc0 sc1"
                                 :: "v"(p), "v"(d) : "memory");
                }
            }
            // ---- early-issue next step's stage loads ----
            #pragma unroll
            for (int p = 0; p < 16; ++p) {
                const unsigned* sp = dst + (size_t)(b0 + p) * HID + tid * 4;
                asm volatile("global_load_dwordx4 %0, %1, off sc0 sc1"
                             : "=v"(q[p]) : "v"(sp) : "memory");
            }
        }

        // ---- self-owned fp32 outputs: PLAIN cached stores ----
        #pragma unroll
        for (int j = 0; j < 4; ++j)
            out[(size_t)(b0 + q4 + j) * (SEQ * HID) + (size_t)t * HID + gcol] = hv[j];
        if (t == SEQ - 1) {
            #pragma unroll
            for (int j = 0; j < 4; ++j)
                out[(size_t)OUTSEQ_ELEMS + (size_t)(b0 + q4 + j) * HID + gcol] = hv[j];
        } else {
            #pragma unroll
            for (int j = 0; j < 4; ++j)
                xpv[j] = xpn[j];
        }
    }
}

extern "C" void kernel_launch(void* const* d_in, const int* in_sizes, int n_in,
                              void* d_out, int out_size, void* d_ws, size_t ws_size,
                              hipStream_t stream)
{
    const float* input = (const float*)d_in[0];
    const float* h0    = (const float*)d_in[1];
    const float* W     = (const float*)d_in[2];
    const float* bias  = (const float*)d_in[3];
    float* out = (float*)d_out;

    unsigned* hb0 = (unsigned*)d_ws;                       // 256 KB
    unsigned* hb1 = hb0 + (size_t)BATCH * HID;             // 256 KB

    // Wipe tag space (0xFFFF never equals a valid tag 0..511). In-graph,
    // so every replay self-cleans; required for the first un-poisoned launch.
    hipMemsetAsync(d_ws, 0xFF, (size_t)2 * BATCH * HID * sizeof(unsigned), stream);

    dim3 gA(HID / 128, (BATCH * SEQ) / 128);   // (8, 256)
    xproj_gemm<<<gA, dim3(256), 0, stream>>>(input, W, bias, out);

    rnn_flow<<<dim3(NBLK), dim3(256), 0, stream>>>(W, h0, out, hb0, hb1);
}